// Round 7
// baseline (43.770 us; speedup 1.0000x reference)
//
#include <hip/hip_runtime.h>

// CP_Based: out[b,u] = rsqrt(prod_f (1+X^2)) * sum_r prod_f (k0[r,f,u] + X[b,f]*k1[r,f,u])
// X: [B,32] f32, kernel: [2,10,32,8] f32, out: [B,8] f32
//
// R1-R6 model: any design that STREAMS K per row-batch pays ~28-31us regardless
// of path (scalar narrow/wide, VMEM, LDS) -- 40MB of K broadcast is the cost.
// This round inverts the dataflow: K is RESIDENT in VGPRs (80 (rank,unit) pairs
// distributed one per lane; 128 VGPRs/lane, gathered once), and X streams on the
// scalar pipe (2 s_load_dwordx16 per row, 16.8MB once). Per row: in-lane 32-factor
// product (pk f-pairs, 4 ILP chains), rank-sum via 3 shfl_xor, uniform norm,
// 8-lane coalesced store. No contended broadcast pipe remains; VALU-bound.

typedef float f32x2 __attribute__((ext_vector_type(2)));

#define F 32
#define RANK 10
#define UNITS 8
#define RPW 64           // rows per wave
#define WPB 4            // waves per block

__global__ __launch_bounds__(64 * WPB) void cp_based_kernel(
    const float* __restrict__ X,
    const float* __restrict__ K,   // [2,10,32,8] flat
    float* __restrict__ out,
    int B)
{
    const int lane = threadIdx.x;          // 0..63
    const int u = lane & 7;                // unit
    const int s = lane >> 3;               // slot: set1 rank = s; set2 rank = 8+s (s<2)
    const int wy = __builtin_amdgcn_readfirstlane(threadIdx.y);
    const int wid = blockIdx.x * WPB + wy;
    const long row0 = (long)wid * RPW;

    // ---- one-time K gather into VGPRs, packed over (f, f+1) pairs
    f32x2 k0a[16], k1a[16], k0b[16], k1b[16];
    {
        const int r1 = s;
#pragma unroll
        for (int fp = 0; fp < 16; ++fp) {
            const int f0 = 2 * fp;
            k0a[fp] = f32x2{K[((0 * RANK + r1) * F + f0) * UNITS + u],
                            K[((0 * RANK + r1) * F + f0 + 1) * UNITS + u]};
            k1a[fp] = f32x2{K[((1 * RANK + r1) * F + f0) * UNITS + u],
                            K[((1 * RANK + r1) * F + f0 + 1) * UNITS + u]};
        }
    }
    if (s < 2) {
        const int r2 = 8 + s;
#pragma unroll
        for (int fp = 0; fp < 16; ++fp) {
            const int f0 = 2 * fp;
            k0b[fp] = f32x2{K[((0 * RANK + r2) * F + f0) * UNITS + u],
                            K[((0 * RANK + r2) * F + f0 + 1) * UNITS + u]};
            k1b[fp] = f32x2{K[((1 * RANK + r2) * F + f0) * UNITS + u],
                            K[((1 * RANK + r2) * F + f0 + 1) * UNITS + u]};
        }
    } else {
#pragma unroll
        for (int fp = 0; fp < 16; ++fp) {
            k0b[fp] = f32x2{0.f, 0.f};
            k1b[fp] = f32x2{0.f, 0.f};
        }
    }

    const f32x2 one2 = {1.f, 1.f};

#pragma unroll 2
    for (int i = 0; i < RPW; ++i) {
        // X row: wave-uniform address -> scalar loads (s_load_dwordx16 x2)
        const float* xr = X + (row0 + i) * F;
        f32x2 xp[16];
#pragma unroll
        for (int fp = 0; fp < 16; ++fp)
            xp[fp] = *reinterpret_cast<const f32x2*>(xr + 2 * fp);

        // 4 independent product chains per stream (ILP depth 4)
        f32x2 ta[4], tb[4], tn[4];
#pragma unroll
        for (int q = 0; q < 4; ++q) {
            ta[q] = xp[q] * k1a[q] + k0a[q];
            tb[q] = xp[q] * k1b[q] + k0b[q];
            tn[q] = xp[q] * xp[q] + one2;
        }
#pragma unroll
        for (int fp = 4; fp < 16; ++fp) {
            const int q = fp & 3;
            ta[q] *= xp[fp] * k1a[fp] + k0a[fp];
            tb[q] *= xp[fp] * k1b[fp] + k0b[fp];
            tn[q] *= xp[fp] * xp[fp] + one2;
        }
        ta[0] *= ta[1]; ta[2] *= ta[3]; ta[0] *= ta[2];
        tb[0] *= tb[1]; tb[2] *= tb[3]; tb[0] *= tb[2];
        tn[0] *= tn[1]; tn[2] *= tn[3]; tn[0] *= tn[2];

        // per-lane (rank,unit) contribution: set1 + set2 (set2 = 0 for s>=2)
        float P = __builtin_fmaf(tb[0][0], tb[0][1], ta[0][0] * ta[0][1]);
        float nrm = tn[0][0] * tn[0][1];

        // rank-sum across slots (lane bits 3,4,5)
        P += __shfl_xor(P, 8);
        P += __shfl_xor(P, 16);
        P += __shfl_xor(P, 32);

        if (s == 0)
            out[(row0 + i) * UNITS + u] = P * __builtin_amdgcn_rsqf(nrm);
    }
}

extern "C" void kernel_launch(void* const* d_in, const int* in_sizes, int n_in,
                              void* d_out, int out_size, void* d_ws, size_t ws_size,
                              hipStream_t stream) {
    const float* X = (const float*)d_in[0];
    const float* K = (const float*)d_in[1];
    float* out = (float*)d_out;
    const int B = in_sizes[0] / F;   // 131072

    dim3 block(64, WPB);                 // 256 threads
    dim3 grid(B / (RPW * WPB));          // 512 blocks
    hipLaunchKernelGGL(cp_based_kernel, grid, block, 0, stream, X, K, out, B);
}

// Round 8
// 32.389 us; speedup vs baseline: 1.3514x; 1.3514x over previous
//
#include <hip/hip_runtime.h>

// CP_Based: out[b,u] = rsqrt(prod_f (1+X^2)) * sum_r prod_f (k0[r,f,u] + X[b,f]*k1[r,f,u])
// X: [B,32] f32, kernel: [2,10,32,8] f32, out: [B,8] f32
//
// Inverted dataflow (R7) with fixes:
//  - K resident in VGPRs, PINNED via opaque asm (R7's VGPR=76 proved the
//    compiler rematerialized the K loads -> K streamed per-row again).
//  - X tile VMEM-loaded coalesced at wave start: computes all row norms
//    lane-parallel ONCE (saves 32 pk/row) and warms L2 so per-row s_loads
//    hit L2 (~220cy) not HBM (~900cy).
//  - RPW=32 (4096 waves, ~3/SIMD at VGPR~160) + A/B 2-deep row prefetch.

typedef float f32x2 __attribute__((ext_vector_type(2)));
typedef float f32x4 __attribute__((ext_vector_type(4)));

#define F 32
#define RANK 10
#define UNITS 8
#define RPW 32           // rows per wave
#define WPB 4            // waves per block

__global__ __launch_bounds__(64 * WPB) void cp_based_kernel(
    const float* __restrict__ X,
    const float* __restrict__ K,   // [2,10,32,8] flat
    float* __restrict__ out,
    int B)
{
    const int lane = threadIdx.x;          // 0..63
    const int u = lane & 7;                // unit
    const int s = lane >> 3;               // rank-slot: set1 r=s; set2 r=8+s (s<2)
    const int wy = __builtin_amdgcn_readfirstlane(threadIdx.y);
    const int wid = blockIdx.x * WPB + wy;
    const long row0 = (long)wid * RPW;

    // ---- coalesced VMEM X tile load: lane l holds X[row0 + l/2, 16*(l&1)+0..15]
    f32x4 xb[4];
    {
        const float* xp = X + (row0 + (lane >> 1)) * F + 16 * (lane & 1);
#pragma unroll
        for (int j = 0; j < 4; ++j)
            xb[j] = *reinterpret_cast<const f32x4*>(xp + 4 * j);
    }

    // ---- one-time K gather into VGPRs (dword gathers, L2-resident K)
    f32x2 k0a[16], k1a[16], k0b[16], k1b[16];
    {
        const int r1 = s;
#pragma unroll
        for (int fp = 0; fp < 16; ++fp) {
            const int f0 = 2 * fp;
            k0a[fp] = f32x2{K[((0 * RANK + r1) * F + f0) * UNITS + u],
                            K[((0 * RANK + r1) * F + f0 + 1) * UNITS + u]};
            k1a[fp] = f32x2{K[((1 * RANK + r1) * F + f0) * UNITS + u],
                            K[((1 * RANK + r1) * F + f0 + 1) * UNITS + u]};
        }
    }
    if (s < 2) {
        const int r2 = 8 + s;
#pragma unroll
        for (int fp = 0; fp < 16; ++fp) {
            const int f0 = 2 * fp;
            k0b[fp] = f32x2{K[((0 * RANK + r2) * F + f0) * UNITS + u],
                            K[((0 * RANK + r2) * F + f0 + 1) * UNITS + u]};
            k1b[fp] = f32x2{K[((1 * RANK + r2) * F + f0) * UNITS + u],
                            K[((1 * RANK + r2) * F + f0 + 1) * UNITS + u]};
        }
    } else {
#pragma unroll
        for (int fp = 0; fp < 16; ++fp) {
            k0b[fp] = f32x2{0.f, 0.f};
            k1b[fp] = f32x2{0.f, 0.f};
        }
    }
    // Pin K values in registers: opaque redefinition blocks rematerialization.
#pragma unroll
    for (int fp = 0; fp < 16; ++fp) {
        asm volatile("" : "+v"(k0a[fp]), "+v"(k1a[fp]));
        asm volatile("" : "+v"(k0b[fp]), "+v"(k1b[fp]));
    }

    // ---- lane-parallel row norms: nrm(row l/2) from 16 factors/lane, pair-merge
    float rsqv;
    {
        f32x4 na = xb[0] * xb[0] + f32x4{1.f, 1.f, 1.f, 1.f};
        f32x4 nb = xb[1] * xb[1] + f32x4{1.f, 1.f, 1.f, 1.f};
        f32x4 nc = xb[2] * xb[2] + f32x4{1.f, 1.f, 1.f, 1.f};
        f32x4 nd = xb[3] * xb[3] + f32x4{1.f, 1.f, 1.f, 1.f};
        f32x4 nv = (na * nb) * (nc * nd);
        float npl = (nv[0] * nv[1]) * (nv[2] * nv[3]);
        npl *= __shfl_xor(npl, 1);           // combine the two 16-f halves
        rsqv = __builtin_amdgcn_rsqf(npl);   // lane 2i holds rsq(nrm[row i])
    }

    const f32x2 one2 = {1.f, 1.f};

    // per-row compute from SGPR X buffer xq[8] (f32x4 quads)
    auto COMPUTE = [&](const f32x4* xq, int i) {
        f32x2 ta[4], tb[4];
#pragma unroll
        for (int q = 0; q < 4; ++q) {
            f32x2 xp = {xq[q >> 1][2 * (q & 1)], xq[q >> 1][2 * (q & 1) + 1]};
            ta[q] = xp * k1a[q] + k0a[q];
            tb[q] = xp * k1b[q] + k0b[q];
        }
#pragma unroll
        for (int fp = 4; fp < 16; ++fp) {
            const int q = fp & 3;
            f32x2 xp = {xq[fp >> 1][2 * (fp & 1)], xq[fp >> 1][2 * (fp & 1) + 1]};
            ta[q] *= xp * k1a[fp] + k0a[fp];
            tb[q] *= xp * k1b[fp] + k0b[fp];
        }
        ta[0] *= ta[1]; ta[2] *= ta[3]; ta[0] *= ta[2];
        tb[0] *= tb[1]; tb[2] *= tb[3]; tb[0] *= tb[2];
        float P = __builtin_fmaf(tb[0][0], tb[0][1], ta[0][0] * ta[0][1]);
        P += __shfl_xor(P, 8);
        P += __shfl_xor(P, 16);
        P += __shfl_xor(P, 32);
        float srsq = __uint_as_float(
            __builtin_amdgcn_readlane(__float_as_uint(rsqv), 2 * i));
        if (s == 0)
            out[(row0 + i) * UNITS + u] = P * srsq;
    };

    auto LOADROW = [&](f32x4* dst, int i) {
        const f32x4* xr4 = reinterpret_cast<const f32x4*>(X + (row0 + i) * F);
#pragma unroll
        for (int j = 0; j < 8; ++j) dst[j] = xr4[j];   // uniform addr -> s_load
    };

    f32x4 xA[8], xB[8];
    LOADROW(xA, 0);
#pragma unroll
    for (int i = 0; i < RPW; i += 2) {
        LOADROW(xB, i + 1);
        COMPUTE(xA, i);
        LOADROW(xA, i + 2 < RPW ? i + 2 : RPW - 1);
        COMPUTE(xB, i + 1);
    }
}

extern "C" void kernel_launch(void* const* d_in, const int* in_sizes, int n_in,
                              void* d_out, int out_size, void* d_ws, size_t ws_size,
                              hipStream_t stream) {
    const float* X = (const float*)d_in[0];
    const float* K = (const float*)d_in[1];
    float* out = (float*)d_out;
    const int B = in_sizes[0] / F;   // 131072

    dim3 block(64, WPB);                 // 256 threads
    dim3 grid(B / (RPW * WPB));          // 1024 blocks
    hipLaunchKernelGGL(cp_based_kernel, grid, block, 0, stream, X, K, out, B);
}